// Round 4
// baseline (102.332 us; speedup 1.0000x reference)
//
#include <hip/hip_runtime.h>

#define HH 479
#define WW 639
#define BATCH 8
#define NBLK (20 * 30 * 8)   // 4800 blocks

// Tile: 32 cols x 16 rows per block, 256 threads, 2 px/thread.
// R14: SINGLE-PASS FUSED k. R13 (LDS-instr halving) was neutral -> LDS pipe
// is not the binder; R1's VALUBusy=51% says VALU-issue + stalls are. The
// k-loop duplicated all address/weight/loop machinery and 2 barriers. Now
// pred+gt are processed in ONE traversal with dual cs buffers: stage 1
// shares col addresses + b-weights across both inputs (10 accumulators),
// stage 2 shares e/aw/aw^2 per tap, n0A stash + its barrier gone.
// Barriers 5 -> 3. LDS ~32.5 KB -> 4 blocks/CU static; R11/R12 showed
// achieved occupancy ~50% regardless of static limit, so cost ~nil.
// R13: record = float4{S1,Sb,Sbb,T1} + float Tb; b128 quad pattern is
// conflict-free (8 lanes/quad), Tb has odd ty-stride 39 (2-way free).
// R12: stage 1 = 156 tasks (39 cols x 4 row-groups), init 8-row sum + 3
// slide-by-1; sd row stride 41. R8: adjacent px share 7/8 window cols ->
// 7 shared core taps + 1 unique tap per px. Solve (f32, R5-validated):
// centered A_hat + Sherman-Morrison => same unit normal as (M+eps I)^-1 s.
// Retirement: per-block STORE into acc[block_id] (no memset), tiny finalize.
// (R2/R3: fence+counter readback poisons retirement.)

__device__ __forceinline__ void solve_normal(
    float xx, float xy, float xz, float yy, float yz, float zz,
    float xs, float ys, float zs,
    float a_c, float b_c, float d0,
    float* nx, float* ny, float* nz)
{
    const float EPSV = 1e-6f;
    const float inv64 = 1.0f / 64.0f;
    float hx = xs * inv64, hy = ys * inv64, hz = zs * inv64;
    float cxx = fmaf(-hx, xs, xx) + EPSV;
    float cxy = fmaf(-hx, ys, xy);
    float cxz = fmaf(-hx, zs, xz);
    float cyy = fmaf(-hy, ys, yy) + EPSV;
    float cyz = fmaf(-hy, zs, yz);
    float czz = fmaf(-hz, zs, zz) + EPSV;
    float c00 = fmaf(cyy, czz, -cyz * cyz);
    float c01 = fmaf(cxz, cyz, -cxy * czz);
    float c02 = fmaf(cxy, cyz, -cxz * cyy);
    float c11 = fmaf(cxx, czz, -cxz * cxz);
    float c12 = fmaf(cxy, cxz, -cxx * cyz);
    float c22 = fmaf(cxx, cyy, -cxy * cxy);
    float m0 = fmaf(c00, xs, fmaf(c01, ys, c02 * zs));
    float m1 = fmaf(c01, xs, fmaf(c11, ys, c12 * zs));
    float m2 = fmaf(c02, xs, fmaf(c12, ys, c22 * zs));
    float g  = fmaf(m0, a_c, fmaf(m1, b_c, m2));   // sign of dot(n, xyz), d0>0
    float inv = rsqrtf(fmaf(m0, m0, fmaf(m1, m1, m2 * m2)));
    if (g > 0.0f) inv = -inv;
    if (!(d0 > 0.0f)) inv = 0.0f;                  // where(depth>0, n, 0)
    *nx = m0 * inv; *ny = m1 * inv; *nz = m2 * inv;
}

__global__ __launch_bounds__(256, 4)
void ppal_main(const float* __restrict__ pred, const float* __restrict__ gt,
               double* __restrict__ acc)
{
    const int tx = threadIdx.x;        // 0..15
    const int ty = threadIdx.y;        // 0..15
    const int tid = ty * 16 + tx;
    const int j0 = blockIdx.x * 32;
    const int i0 = blockIdx.y * 16;
    const int b  = blockIdx.z;

    const float invFX = 1.0f / 518.857f;
    const float invFY = 1.0f / 519.469f;

    // depth tiles: rows i0-4..i0+18 (23), cols j0-4..j0+34 (39); stride 41
    __shared__ float sd[2][23 * 41];
    // DUAL column-sum records: cs4[k][e] = {S1,Sb,Sbb,T1}, csTb[k][e] = Tb,
    // entry e = i*39 + c
    __shared__ float4 cs4[2][624];
    __shared__ float  csTb[2][624];
    __shared__ float  wsum[4];

    const float* src0 = pred + (size_t)b * (HH * WW);
    const float* src1 = gt   + (size_t)b * (HH * WW);
    for (int idx = tid; idx < 23 * 41; idx += 256) {
        int lr = idx / 41, lc = idx - lr * 41;
        int r = i0 - 4 + lr, c = j0 - 4 + lc;
        bool ok = (lc < 39) && (r >= 0) && (r < HH) && (c >= 0) && (c < WW);
        int off = r * WW + c;
        sd[0][idx] = ok ? src0[off] : 0.0f;
        sd[1][idx] = ok ? src1[off] : 0.0f;
    }

    // stage-2 per-thread constants
    float aw[9];
#pragma unroll
    for (int m = 0; m < 9; ++m)
        aw[m] = ((float)(j0 + 2 * tx + m - 4) - 319.5f) * invFX;
    const float bc = ((float)(i0 + ty) - 239.5f) * invFY;
    const int ebase = ty * 39 + 2 * tx;   // record entry for m=0

    __syncthreads();

    // ---- stage 1 (fused k): 156 tasks = 39 cols x 4 row-groups ----
    // task: g = tid/39 in 0..3, c = tid%39, owns output rows 4g..4g+3
    // (init = 8-row sum at row 4g, then 3 slide-by-1 steps), BOTH inputs.
    if (tid < 156) {
        int g = tid / 39;
        int c = tid - 39 * g;
        int rb = 4 * g;
        const float* colA = &sd[0][c];
        const float* colB = &sd[1][c];
        // bv of tile row rb (image row i0 + rb - 4)
        float bv = ((float)(i0 + rb - 4) - 239.5f) * invFY;
        float SA1 = 0.f, SAb = 0.f, SAbb = 0.f, TA1 = 0.f, TAb = 0.f;
        float SB1 = 0.f, SBb = 0.f, SBbb = 0.f, TB1 = 0.f, TBb = 0.f;
#pragma unroll
        for (int r = 0; r < 8; ++r) {
            int ro = (rb + r) * 41;
            float bvr = fmaf((float)r, invFY, bv);
            float dA = colA[ro], dB = colB[ro];
            float bdA = bvr * dA, bdB = bvr * dB;
            TA1 += dA;  TAb += bdA;
            SA1  = fmaf(dA,  dA,  SA1);
            SAb  = fmaf(bdA, dA,  SAb);
            SAbb = fmaf(bdA, bdA, SAbb);
            TB1 += dB;  TBb += bdB;
            SB1  = fmaf(dB,  dB,  SB1);
            SBb  = fmaf(bdB, dB,  SBb);
            SBbb = fmaf(bdB, bdB, SBbb);
        }
        int e = rb * 39 + c;
        cs4[0][e]  = make_float4(SA1, SAb, SAbb, TA1);
        csTb[0][e] = TAb;
        cs4[1][e]  = make_float4(SB1, SBb, SBbb, TB1);
        csTb[1][e] = TBb;
#pragma unroll
        for (int s = 1; s < 4; ++s) {
            // window slides by 1: tile row rb+s-1 leaves, rb+s+7 enters
            int o0 = (rb + s - 1) * 41, o1 = (rb + s + 7) * 41;
            float b0 = fmaf((float)(s - 1), invFY, bv);
            float b1 = fmaf((float)(s + 7), invFY, bv);
            float d0A = colA[o0], d1A = colA[o1];
            float d0B = colB[o0], d1B = colB[o1];
            float bd0A = b0 * d0A, bd1A = b1 * d1A;
            float bd0B = b0 * d0B, bd1B = b1 * d1B;
            TA1 += d1A - d0A;
            TAb += bd1A - bd0A;
            SA1  += fmaf(d1A,  d1A,  -d0A  * d0A);
            SAb  += fmaf(bd1A, d1A,  -bd0A * d0A);
            SAbb += fmaf(bd1A, bd1A, -bd0A * bd0A);
            TB1 += d1B - d0B;
            TBb += bd1B - bd0B;
            SB1  += fmaf(d1B,  d1B,  -d0B  * d0B);
            SBb  += fmaf(bd1B, d1B,  -bd0B * d0B);
            SBbb += fmaf(bd1B, bd1B, -bd0B * bd0B);
            e += 39;
            cs4[0][e]  = make_float4(SA1, SAb, SAbb, TA1);
            csTb[0][e] = TAb;
            cs4[1][e]  = make_float4(SB1, SBb, SBbb, TB1);
            csTb[1][e] = TBb;
        }
    }
    __syncthreads();

    // ---- stage 2 (fused k): shared-core combine + 4 f32 solves ----
    float contrib = 0.0f;
    {
        float SxxA = 0.f, SxyA = 0.f, SxzA = 0.f, SyyA = 0.f, SyzA = 0.f;
        float SzzA = 0.f, SxsA = 0.f, SysA = 0.f, SzsA = 0.f;
        float SxxB = 0.f, SxyB = 0.f, SxzB = 0.f, SyyB = 0.f, SyzB = 0.f;
        float SzzB = 0.f, SxsB = 0.f, SysB = 0.f, SzsB = 0.f;
#pragma unroll
        for (int m = 1; m < 8; ++m) {
            int e = ebase + m;
            float awm = aw[m], awm2 = awm * awm;
            float4 rA = cs4[0][e];          // {S1, Sb, Sbb, T1}
            float  tA = csTb[0][e];
            float4 rB = cs4[1][e];
            float  tB = csTb[1][e];
            SzzA += rA.x;  SyzA += rA.y;  SyyA += rA.z;
            SzsA += rA.w;  SysA += tA;
            SxzA = fmaf(awm,  rA.x, SxzA);
            SxyA = fmaf(awm,  rA.y, SxyA);
            SxsA = fmaf(awm,  rA.w, SxsA);
            SxxA = fmaf(awm2, rA.x, SxxA);
            SzzB += rB.x;  SyzB += rB.y;  SyyB += rB.z;
            SzsB += rB.w;  SysB += tB;
            SxzB = fmaf(awm,  rB.x, SxzB);
            SxyB = fmaf(awm,  rB.y, SxyB);
            SxsB = fmaf(awm,  rB.w, SxsB);
            SxxB = fmaf(awm2, rB.x, SxxB);
        }

        const int i = i0 + ty;
        const bool valid0 = (i < HH);
        const bool valid1 = (i < HH) && (j0 + 2 * tx + 1 < WW);
#pragma unroll
        for (int p = 0; p < 2; ++p) {
            int m = (p == 0) ? 0 : 8;               // unique tap
            int e = ebase + m;
            float awm = aw[m], awm2 = awm * awm;
            int doff = (ty + 4) * 41 + (2 * tx + p + 4);

            float4 rA = cs4[0][e];
            float  tA = csTb[0][e];
            float nA[3];
            solve_normal(fmaf(awm2, rA.x, SxxA), fmaf(awm, rA.y, SxyA),
                         fmaf(awm, rA.x, SxzA),  SyyA + rA.z,
                         SyzA + rA.y,            SzzA + rA.x,
                         fmaf(awm, rA.w, SxsA),  SysA + tA,
                         SzsA + rA.w,
                         aw[4 + p], bc, sd[0][doff], &nA[0], &nA[1], &nA[2]);

            float4 rB = cs4[1][e];
            float  tB = csTb[1][e];
            float nB[3];
            solve_normal(fmaf(awm2, rB.x, SxxB), fmaf(awm, rB.y, SxyB),
                         fmaf(awm, rB.x, SxzB),  SyyB + rB.z,
                         SyzB + rB.y,            SzzB + rB.x,
                         fmaf(awm, rB.w, SxsB),  SysB + tB,
                         SzsB + rB.w,
                         aw[4 + p], bc, sd[1][doff], &nB[0], &nB[1], &nB[2]);

            float cp = fabsf(nA[0] - nB[0]) + fabsf(nA[1] - nB[1])
                     + fabsf(nA[2] - nB[2]);
            bool v = (p == 0) ? valid0 : valid1;
            contrib += v ? cp : 0.0f;
        }
    }

    // ---- reduce: wave shuffle -> LDS -> ONE plain STORE per block ----
    float v = contrib;
#pragma unroll
    for (int off = 32; off > 0; off >>= 1) v += __shfl_down(v, off, 64);
    int wid = tid >> 6, lane = tid & 63;
    if (lane == 0) wsum[wid] = v;
    __syncthreads();
    if (tid == 0) {
        double bs = (double)wsum[0] + (double)wsum[1] + (double)wsum[2] + (double)wsum[3];
        int slot = blockIdx.x + 20 * blockIdx.y + 600 * blockIdx.z;
        acc[slot] = bs;   // unique slot, written every launch -> no memset
    }
}

__global__ void ppal_finalize(const double* __restrict__ acc, float* __restrict__ out)
{
    int tid = threadIdx.x;             // 256 threads, one block
    double v = 0.0;
    for (int s = tid; s < NBLK; s += 256) v += acc[s];
#pragma unroll
    for (int off = 32; off > 0; off >>= 1) v += __shfl_down(v, off, 64);
    __shared__ double wsum[4];
    int wid = tid >> 6, lane = tid & 63;
    if (lane == 0) wsum[wid] = v;
    __syncthreads();
    if (tid == 0)
        out[0] = (float)((wsum[0] + wsum[1] + wsum[2] + wsum[3])
                         * (1.0 / 7345944.0));  // mean over B*3*H*W
}

extern "C" void kernel_launch(void* const* d_in, const int* in_sizes, int n_in,
                              void* d_out, int out_size, void* d_ws, size_t ws_size,
                              hipStream_t stream)
{
    const float* pred = (const float*)d_in[0];
    const float* gt   = (const float*)d_in[1];
    float* out  = (float*)d_out;
    double* acc = (double*)d_ws;

    dim3 grid(20, 30, BATCH);          // 32-col x 16-row tiles = 4800 blocks
    dim3 block(16, 16);
    ppal_main<<<grid, block, 0, stream>>>(pred, gt, acc);
    ppal_finalize<<<1, 256, 0, stream>>>(acc, out);
}

// Round 5
// 101.742 us; speedup vs baseline: 1.0058x; 1.0058x over previous
//
#include <hip/hip_runtime.h>

#define HH 479
#define WW 639
#define BATCH 8
#define NBLK (20 * 60 * 8)   // 9600 blocks

// Tile: 32 cols x 8 rows per block, 128 threads (16x8), 2 px/thread.
// R15: CONCURRENCY, not instruction count. Evidence: R13 (LDS instr cut
// 2.5x) neutral; R14 (VALU/barrier cut, but 8->4 blocks/CU) regressed;
// static issue model says ~70% of ppal_main is stall. So: back to R13's
// k-phased structure, tile halved to 32x8 -> LDS 11.2 KB -> 14 blocks/CU
// (28 waves, launch_bounds(128,7)) vs 8; barriers sync 2 waves not 4;
// 9600 blocks smooth the tail. Same total record count (312x9600 =
// 624x4800), same per-record slide cost (39 cols x 2 chains-of-4).
// Bank check at ty in 0..7: b128 quad q=(7ty+2tx+m) mod 8 -> exactly
// 8 lanes/quad (conflict-free floor); csTb odd-ish stride stays <=2-way.
// R13: record = float4{S1,Sb,Sbb,T1} + float Tb (2 LDS instr per record).
// R12: k-phased cs (one buffer reused across pred/gt phases); sd row
// stride 41 (odd). R8: adjacent px share 7/8 window cols -> 7 shared core
// taps + 1 unique tap per px. Solve (f32, R5-validated): centered A_hat +
// Sherman-Morrison => same unit normal as (M+eps I)^-1 s.
// Retirement: per-block STORE into acc[block_id] (no memset), tiny finalize.
// (R2/R3: fence+counter readback poisons retirement.)

__device__ __forceinline__ void solve_normal(
    float xx, float xy, float xz, float yy, float yz, float zz,
    float xs, float ys, float zs,
    float a_c, float b_c, float d0,
    float* nx, float* ny, float* nz)
{
    const float EPSV = 1e-6f;
    const float inv64 = 1.0f / 64.0f;
    float hx = xs * inv64, hy = ys * inv64, hz = zs * inv64;
    float cxx = fmaf(-hx, xs, xx) + EPSV;
    float cxy = fmaf(-hx, ys, xy);
    float cxz = fmaf(-hx, zs, xz);
    float cyy = fmaf(-hy, ys, yy) + EPSV;
    float cyz = fmaf(-hy, zs, yz);
    float czz = fmaf(-hz, zs, zz) + EPSV;
    float c00 = fmaf(cyy, czz, -cyz * cyz);
    float c01 = fmaf(cxz, cyz, -cxy * czz);
    float c02 = fmaf(cxy, cyz, -cxz * cyy);
    float c11 = fmaf(cxx, czz, -cxz * cxz);
    float c12 = fmaf(cxy, cxz, -cxx * cyz);
    float c22 = fmaf(cxx, cyy, -cxy * cxy);
    float m0 = fmaf(c00, xs, fmaf(c01, ys, c02 * zs));
    float m1 = fmaf(c01, xs, fmaf(c11, ys, c12 * zs));
    float m2 = fmaf(c02, xs, fmaf(c12, ys, c22 * zs));
    float g  = fmaf(m0, a_c, fmaf(m1, b_c, m2));   // sign of dot(n, xyz), d0>0
    float inv = rsqrtf(fmaf(m0, m0, fmaf(m1, m1, m2 * m2)));
    if (g > 0.0f) inv = -inv;
    if (!(d0 > 0.0f)) inv = 0.0f;                  // where(depth>0, n, 0)
    *nx = m0 * inv; *ny = m1 * inv; *nz = m2 * inv;
}

__global__ __launch_bounds__(128, 7)
void ppal_main(const float* __restrict__ pred, const float* __restrict__ gt,
               double* __restrict__ acc)
{
    const int tx = threadIdx.x;        // 0..15
    const int ty = threadIdx.y;        // 0..7
    const int tid = ty * 16 + tx;      // 0..127
    const int j0 = blockIdx.x * 32;
    const int i0 = blockIdx.y * 8;
    const int b  = blockIdx.z;

    const float invFX = 1.0f / 518.857f;
    const float invFY = 1.0f / 519.469f;

    // depth tiles: rows i0-4..i0+10 (15), cols j0-4..j0+34 (39); stride 41
    __shared__ float sd[2][15 * 41];
    // SINGLE-k column-sum records: cs4[e] = {S1,Sb,Sbb,T1}, csTb[e] = Tb,
    // entry e = i*39 + c, i in 0..7
    __shared__ float4 cs4[312];
    __shared__ float  csTb[312];
    __shared__ float  wsum[2];

    const float* src0 = pred + (size_t)b * (HH * WW);
    const float* src1 = gt   + (size_t)b * (HH * WW);
    for (int idx = tid; idx < 15 * 41; idx += 128) {
        int lr = idx / 41, lc = idx - lr * 41;
        int r = i0 - 4 + lr, c = j0 - 4 + lc;
        bool ok = (lc < 39) && (r >= 0) && (r < HH) && (c >= 0) && (c < WW);
        int off = r * WW + c;
        sd[0][idx] = ok ? src0[off] : 0.0f;
        sd[1][idx] = ok ? src1[off] : 0.0f;
    }

    // stage-2 per-thread constants (live across both phases)
    float aw[9];
#pragma unroll
    for (int m = 0; m < 9; ++m)
        aw[m] = ((float)(j0 + 2 * tx + m - 4) - 319.5f) * invFX;
    const float bc = ((float)(i0 + ty) - 239.5f) * invFY;
    const int ebase = ty * 39 + 2 * tx;   // record entry for m=0

    float n0A[3], n1A[3];   // input-0 normals for pixels 0,1
    float contrib = 0.0f;

    __syncthreads();

#pragma unroll
    for (int k = 0; k < 2; ++k) {
        // ---- stage 1 (phase k): 78 tasks = 39 cols x 2 row-groups ----
        // task: g = t/39 in 0..1, c = t%39, owns output rows 4g..4g+3
        // (init = 8-row sum at row 4g, then 3 slide-by-1 steps).
        if (tid < 78) {
            int g = tid / 39;
            int c = tid - 39 * g;
            int rb = 4 * g;
            const float* col = &sd[k][c];
            // bv of tile-local row rb (image row i0 + rb - 4)
            float bv = ((float)(i0 + rb - 4) - 239.5f) * invFY;
            float S1 = 0.f, Sb = 0.f, Sbb = 0.f, T1 = 0.f, Tb = 0.f;
#pragma unroll
            for (int r = 0; r < 8; ++r) {
                float d  = col[(rb + r) * 41];
                float bvr = fmaf((float)r, invFY, bv);
                float bd = bvr * d;
                T1 += d;  Tb += bd;
                S1  = fmaf(d,  d,  S1);
                Sb  = fmaf(bd, d,  Sb);
                Sbb = fmaf(bd, bd, Sbb);
            }
            int e = rb * 39 + c;
            cs4[e]  = make_float4(S1, Sb, Sbb, T1);
            csTb[e] = Tb;
#pragma unroll
            for (int s = 1; s < 4; ++s) {
                // window slides by 1: tile row rb+s-1 leaves, rb+s+7 enters
                float d0 = col[(rb + s - 1) * 41];
                float d1 = col[(rb + s + 7) * 41];
                float b0 = fmaf((float)(s - 1), invFY, bv);
                float b1 = fmaf((float)(s + 7), invFY, bv);
                float bd0 = b0 * d0, bd1 = b1 * d1;
                T1 += d1 - d0;
                Tb += bd1 - bd0;
                S1  += fmaf(d1,  d1,  -d0  * d0);
                Sb  += fmaf(bd1, d1,  -bd0 * d0);
                Sbb += fmaf(bd1, bd1, -bd0 * bd0);
                e += 39;
                cs4[e]  = make_float4(S1, Sb, Sbb, T1);
                csTb[e] = Tb;
            }
        }
        __syncthreads();

        // ---- stage 2 (phase k): shared-core combine + 2 f32 solves ----
        {
            float Sxx = 0.f, Sxy = 0.f, Sxz = 0.f, Syy = 0.f, Syz = 0.f;
            float Szz = 0.f, Sxs = 0.f, Sys = 0.f, Szs = 0.f;
#pragma unroll
            for (int m = 1; m < 8; ++m) {
                int e = ebase + m;
                float4 r = cs4[e];           // {S1, Sb, Sbb, T1}
                float  tb = csTb[e];
                Szz += r.x;  Syz += r.y;  Syy += r.z;
                Szs += r.w;  Sys += tb;
                Sxz = fmaf(aw[m],         r.x, Sxz);
                Sxy = fmaf(aw[m],         r.y, Sxy);
                Sxs = fmaf(aw[m],         r.w, Sxs);
                Sxx = fmaf(aw[m] * aw[m], r.x, Sxx);
            }

            float nn[2][3];
#pragma unroll
            for (int p = 0; p < 2; ++p) {
                int m = (p == 0) ? 0 : 8;               // unique tap
                int e = ebase + m;
                float4 r = cs4[e];
                float  tb = csTb[e];
                float xx = fmaf(aw[m] * aw[m], r.x, Sxx);
                float xy = fmaf(aw[m], r.y, Sxy);
                float xz = fmaf(aw[m], r.x, Sxz);
                float yy = Syy + r.z;
                float yz = Syz + r.y;
                float zz = Szz + r.x;
                float xs = fmaf(aw[m], r.w, Sxs);
                float ys = Sys + tb;
                float zs = Szs + r.w;
                float d0 = sd[k][(ty + 4) * 41 + (2 * tx + p + 4)];
                solve_normal(xx, xy, xz, yy, yz, zz, xs, ys, zs,
                             aw[4 + p], bc, d0, &nn[p][0], &nn[p][1], &nn[p][2]);
            }
            if (k == 0) {
                n0A[0] = nn[0][0]; n0A[1] = nn[0][1]; n0A[2] = nn[0][2];
                n1A[0] = nn[1][0]; n1A[1] = nn[1][1]; n1A[2] = nn[1][2];
                __syncthreads();   // all cs reads done -> phase 1 may overwrite
            } else {
                const int i = i0 + ty;
                const bool valid0 = (i < HH);
                const bool valid1 = (i < HH) && (j0 + 2 * tx + 1 < WW);
                float c0 = fabsf(n0A[0] - nn[0][0]) + fabsf(n0A[1] - nn[0][1])
                         + fabsf(n0A[2] - nn[0][2]);
                float c1 = fabsf(n1A[0] - nn[1][0]) + fabsf(n1A[1] - nn[1][1])
                         + fabsf(n1A[2] - nn[1][2]);
                contrib = (valid0 ? c0 : 0.0f) + (valid1 ? c1 : 0.0f);
            }
        }
    }

    // ---- reduce: wave shuffle -> LDS -> ONE plain STORE per block ----
    float v = contrib;
#pragma unroll
    for (int off = 32; off > 0; off >>= 1) v += __shfl_down(v, off, 64);
    int wid = tid >> 6, lane = tid & 63;
    if (lane == 0) wsum[wid] = v;
    __syncthreads();
    if (tid == 0) {
        double bs = (double)wsum[0] + (double)wsum[1];
        int slot = blockIdx.x + 20 * blockIdx.y + 1200 * blockIdx.z;
        acc[slot] = bs;   // unique slot, written every launch -> no memset
    }
}

__global__ void ppal_finalize(const double* __restrict__ acc, float* __restrict__ out)
{
    int tid = threadIdx.x;             // 256 threads, one block
    double v = 0.0;
    for (int s = tid; s < NBLK; s += 256) v += acc[s];
#pragma unroll
    for (int off = 32; off > 0; off >>= 1) v += __shfl_down(v, off, 64);
    __shared__ double wsum[4];
    int wid = tid >> 6, lane = tid & 63;
    if (lane == 0) wsum[wid] = v;
    __syncthreads();
    if (tid == 0)
        out[0] = (float)((wsum[0] + wsum[1] + wsum[2] + wsum[3])
                         * (1.0 / 7345944.0));  // mean over B*3*H*W
}

extern "C" void kernel_launch(void* const* d_in, const int* in_sizes, int n_in,
                              void* d_out, int out_size, void* d_ws, size_t ws_size,
                              hipStream_t stream)
{
    const float* pred = (const float*)d_in[0];
    const float* gt   = (const float*)d_in[1];
    float* out  = (float*)d_out;
    double* acc = (double*)d_ws;

    dim3 grid(20, 60, BATCH);          // 32-col x 8-row tiles = 9600 blocks
    dim3 block(16, 8);
    ppal_main<<<grid, block, 0, stream>>>(pred, gt, acc);
    ppal_finalize<<<1, 256, 0, stream>>>(acc, out);
}